// Round 1
// baseline (1920.280 us; speedup 1.0000x reference)
//
#include <hip/hip_runtime.h>

#define DIM   256
#define NH    4
#define HC    64
#define NTOK  49
#define XPAD  264   // xb row stride in bf16 elems (528 B = 33*16, bank offset 4/row)
#define APAD  72    // attn buffer row stride (144 B = 9*16, bank offset 4/row)

typedef __attribute__((ext_vector_type(8))) short bf16x8;
typedef __attribute__((ext_vector_type(4))) short bf16x4;
typedef __attribute__((ext_vector_type(4))) float f32x4;

__device__ __forceinline__ short f2bf(float f) {
    union { float f; unsigned u; } v; v.f = f;
    unsigned r = v.u + 0x7fffu + ((v.u >> 16) & 1u);   // RNE
    return (short)(r >> 16);
}

__device__ __forceinline__ float wred_sum16(float v) {
    v += __shfl_xor(v, 1); v += __shfl_xor(v, 2);
    v += __shfl_xor(v, 4); v += __shfl_xor(v, 8);
    return v;
}
__device__ __forceinline__ float wred_max16(float v) {
    v = fmaxf(v, __shfl_xor(v, 1)); v = fmaxf(v, __shfl_xor(v, 2));
    v = fmaxf(v, __shfl_xor(v, 4)); v = fmaxf(v, __shfl_xor(v, 8));
    return v;
}

// Weight standardization: per (input-row k, output-head h) group of 64,
// Wt[n][k] = (W[k][n] - mean) / (popstd * 16), stored transposed bf16.
__global__ void prep_w(const float* __restrict__ W, short* __restrict__ Wt) {
    const int k = blockIdx.x;
    const int lane = threadIdx.x;   // 64 threads = 1 wave
    const float* row = W + k * DIM;
    #pragma unroll
    for (int h = 0; h < NH; ++h) {
        float w = row[h * HC + lane];
        float s1 = w, s2 = w * w;
        #pragma unroll
        for (int off = 1; off < 64; off <<= 1) {
            s1 += __shfl_xor(s1, off);
            s2 += __shfl_xor(s2, off);
        }
        float m = s1 * 0.015625f;
        float var = s2 * 0.015625f - m * m;
        float inv = rsqrtf(fmaxf(var, 1e-30f)) * 0.0625f;  // 1/(std*sqrt(256))
        Wt[(h * HC + lane) * DIM + k] = f2bf((w - m) * inv);
    }
}

__global__ void prep_b(const float* __restrict__ b, float* __restrict__ bo) {
    const int h = blockIdx.x;
    const int lane = threadIdx.x;
    float w = b[h * HC + lane];
    float s1 = w, s2 = w * w;
    #pragma unroll
    for (int off = 1; off < 64; off <<= 1) {
        s1 += __shfl_xor(s1, off);
        s2 += __shfl_xor(s2, off);
    }
    float m = s1 * 0.015625f;
    float var = s2 * 0.015625f - m * m;
    float inv = rsqrtf(fmaxf(var, 1e-30f)) * 0.0625f;
    bo[h * HC + lane] = (w - m) * inv;
}

// One block = one batch item. 4 waves; wave w owns token rows [16w, 16w+16).
// M padded 49 -> 64 (pad rows zeroed in xb; pad key-cols masked in softmax).
__global__ __launch_bounds__(256, 2) void irmb_main(
    const float* __restrict__ x,
    const short* __restrict__ Wt,    // 5 x [256][256] bf16, transposed (n-major)
    const float* __restrict__ Bias,  // 5 x [256] fp32, standardized
    float* __restrict__ out)
{
    __shared__ short xb[64][XPAD];   // x (then x1, then x3) in bf16, row-private per wave
    __shared__ short qP[64][APAD];   // q, later P (row-private writes/reads)
    __shared__ short kb[64][APAD];   // k (shared reads)
    __shared__ short vt[64][APAD];   // v transposed [channel][token] (shared reads)

    const int tid  = threadIdx.x;
    const int w    = tid >> 6;
    const int lane = tid & 63;
    const int l15  = lane & 15;
    const int qd   = lane >> 4;
    const int arow = 16 * w + l15;      // A-fragment row for this lane

    const float* xblk = x + (size_t)blockIdx.x * (NTOK * DIM);
    float* oblk = out + (size_t)blockIdx.x * (NTOK * DIM);

    // ---- stage x -> bf16 LDS (own rows; pad rows zero) ----
    #pragma unroll
    for (int rr = 0; rr < 16; ++rr) {
        int row = 16 * w + rr;
        f32x4 v = {0.f, 0.f, 0.f, 0.f};
        if (row < NTOK) v = *(const f32x4*)(xblk + row * DIM + 4 * lane);
        bf16x4 bv;
        bv[0] = f2bf(v[0]); bv[1] = f2bf(v[1]); bv[2] = f2bf(v[2]); bv[3] = f2bf(v[3]);
        *(bf16x4*)&xb[row][4 * lane] = bv;
    }
    __syncthreads();

    float x1[16][4];   // post-attention activations, fp32, C/D layout

    for (int h = 0; h < NH; ++h) {
        const short* Wq = Wt + 0 * DIM * DIM + (h * HC) * DIM;
        const short* Wk = Wt + 1 * DIM * DIM + (h * HC) * DIM;
        const short* Wv = Wt + 2 * DIM * DIM + (h * HC) * DIM;

        // ---- fused q/k/v GEMM for head h (rows 16w, cols h*64..h*64+63) ----
        f32x4 qa[4], ka[4], va[4];
        #pragma unroll
        for (int nt = 0; nt < 4; ++nt) {
            qa[nt] = (f32x4){0.f,0.f,0.f,0.f};
            ka[nt] = (f32x4){0.f,0.f,0.f,0.f};
            va[nt] = (f32x4){0.f,0.f,0.f,0.f};
        }
        for (int kk = 0; kk < 8; ++kk) {
            const int k0 = 32 * kk;
            bf16x8 a = *(const bf16x8*)&xb[arow][k0 + 8 * qd];
            #pragma unroll
            for (int nt = 0; nt < 4; ++nt) {
                const int n = 16 * nt + l15;
                bf16x8 bq = *(const bf16x8*)(Wq + n * DIM + k0 + 8 * qd);
                bf16x8 bk = *(const bf16x8*)(Wk + n * DIM + k0 + 8 * qd);
                bf16x8 bv = *(const bf16x8*)(Wv + n * DIM + k0 + 8 * qd);
                qa[nt] = __builtin_amdgcn_mfma_f32_16x16x32_bf16(a, bq, qa[nt], 0, 0, 0);
                ka[nt] = __builtin_amdgcn_mfma_f32_16x16x32_bf16(a, bk, ka[nt], 0, 0, 0);
                va[nt] = __builtin_amdgcn_mfma_f32_16x16x32_bf16(a, bv, va[nt], 0, 0, 0);
            }
        }

        // ---- epilogue: bias, v-residual, scatter to LDS ----
        float vf[4][4];   // v fp32 (shortcut), kept in regs
        #pragma unroll
        for (int nt = 0; nt < 4; ++nt) {
            const int col = h * HC + 16 * nt + l15;
            const float bq = Bias[0 * DIM + col];
            const float bk = Bias[1 * DIM + col];
            const float bv = Bias[2 * DIM + col];
            #pragma unroll
            for (int r = 0; r < 4; ++r) {
                const int row = 16 * w + 4 * qd + r;
                qP[row][16 * nt + l15] = f2bf(qa[nt][r] + bq);
                kb[row][16 * nt + l15] = f2bf(ka[nt][r] + bk);
                float xh = 0.f;
                if (row < NTOK) xh = xblk[row * DIM + col];
                vf[nt][r] = 0.1f * (va[nt][r] + bv) + 0.95f * xh;
            }
            bf16x4 vp;
            vp[0] = f2bf(vf[nt][0]); vp[1] = f2bf(vf[nt][1]);
            vp[2] = f2bf(vf[nt][2]); vp[3] = f2bf(vf[nt][3]);
            *(bf16x4*)&vt[16 * nt + l15][16 * w + 4 * qd] = vp;
        }
        __syncthreads();   // k, vt complete for all waves

        // ---- S = 0.125 * q @ k^T (rows 16w, all 64 key-cols) ----
        f32x4 sa[4];
        #pragma unroll
        for (int nt = 0; nt < 4; ++nt) sa[nt] = (f32x4){0.f,0.f,0.f,0.f};
        #pragma unroll
        for (int kk = 0; kk < 2; ++kk) {
            const int k0 = 32 * kk;
            bf16x8 a = *(const bf16x8*)&qP[arow][k0 + 8 * qd];
            #pragma unroll
            for (int nt = 0; nt < 4; ++nt) {
                bf16x8 bb = *(const bf16x8*)&kb[16 * nt + l15][k0 + 8 * qd];
                sa[nt] = __builtin_amdgcn_mfma_f32_16x16x32_bf16(a, bb, sa[nt], 0, 0, 0);
            }
        }

        // ---- softmax over key dim (mask cols >= 49) ----
        float pmat[4][4];
        #pragma unroll
        for (int r = 0; r < 4; ++r) {
            float vals[4];
            #pragma unroll
            for (int nt = 0; nt < 4; ++nt) {
                const int ck = 16 * nt + l15;
                vals[nt] = (ck < NTOK) ? sa[nt][r] * 0.125f : -3.0e38f;
            }
            float mx = fmaxf(fmaxf(vals[0], vals[1]), fmaxf(vals[2], vals[3]));
            mx = wred_max16(mx);
            float sum = 0.f;
            #pragma unroll
            for (int nt = 0; nt < 4; ++nt) {
                const int ck = 16 * nt + l15;
                const float p = (ck < NTOK) ? __expf(vals[nt] - mx) : 0.f;
                pmat[nt][r] = p;
                sum += p;
            }
            sum = wred_sum16(sum);
            const float rs = 1.0f / sum;
            #pragma unroll
            for (int nt = 0; nt < 4; ++nt) pmat[nt][r] *= rs;
        }
        // P overwrites q buffer (rows 16w are private to this wave)
        #pragma unroll
        for (int nt = 0; nt < 4; ++nt) {
            #pragma unroll
            for (int r = 0; r < 4; ++r)
                qP[16 * w + 4 * qd + r][16 * nt + l15] = f2bf(pmat[nt][r]);
        }
        __syncthreads();

        // ---- x_spa = P @ v ; x1 = 0.1*x_spa + 0.95*v ----
        f32x4 pa[4];
        #pragma unroll
        for (int nt = 0; nt < 4; ++nt) pa[nt] = (f32x4){0.f,0.f,0.f,0.f};
        #pragma unroll
        for (int kk = 0; kk < 2; ++kk) {
            const int k0 = 32 * kk;
            bf16x8 a = *(const bf16x8*)&qP[arow][k0 + 8 * qd];
            #pragma unroll
            for (int nt = 0; nt < 4; ++nt) {
                bf16x8 bb = *(const bf16x8*)&vt[16 * nt + l15][k0 + 8 * qd];
                pa[nt] = __builtin_amdgcn_mfma_f32_16x16x32_bf16(a, bb, pa[nt], 0, 0, 0);
            }
        }
        #pragma unroll
        for (int nt = 0; nt < 4; ++nt) {
            #pragma unroll
            for (int r = 0; r < 4; ++r)
                x1[4 * h + nt][r] = 0.1f * pa[nt][r] + 0.95f * vf[nt][r];
        }
        __syncthreads();   // all waves done reading kb/vt before next head's writes
    }

    // ---- FFN: x1 -> xb bf16 (own rows only) ----
    #pragma unroll
    for (int c = 0; c < 16; ++c) {
        #pragma unroll
        for (int r = 0; r < 4; ++r)
            xb[16 * w + 4 * qd + r][16 * c + l15] = f2bf(x1[c][r]);
    }
    __syncthreads();

    const short* Wi = Wt + 3 * DIM * DIM;
    const short* Wo = Wt + 4 * DIM * DIM;

    // ---- FFN-in + residual + sigmoid-residual (two col-halves to cap VGPRs) ----
    #pragma unroll 1
    for (int half = 0; half < 2; ++half) {
        f32x4 f[8];
        #pragma unroll
        for (int c = 0; c < 8; ++c) f[c] = (f32x4){0.f,0.f,0.f,0.f};
        for (int kk = 0; kk < 8; ++kk) {
            const int k0 = 32 * kk;
            bf16x8 a = *(const bf16x8*)&xb[arow][k0 + 8 * qd];
            #pragma unroll
            for (int c = 0; c < 8; ++c) {
                const int n = 16 * (8 * half + c) + l15;
                bf16x8 bb = *(const bf16x8*)(Wi + n * DIM + k0 + 8 * qd);
                f[c] = __builtin_amdgcn_mfma_f32_16x16x32_bf16(a, bb, f[c], 0, 0, 0);
            }
        }
        #pragma unroll
        for (int c = 0; c < 8; ++c) {
            const int cg = 8 * half + c;
            const float bi = Bias[3 * DIM + 16 * cg + l15];
            #pragma unroll
            for (int r = 0; r < 4; ++r) {
                float x2 = 0.1f * (f[c][r] + bi) + 0.95f * x1[cg][r];
                float sg = 1.0f / (1.0f + __expf(-x2));
                x1[cg][r] = 0.95f * x2 + 0.1f * (sg - 0.5f);   // x3
            }
        }
    }
    __syncthreads();

    // ---- x3 -> xb bf16 ----
    #pragma unroll
    for (int c = 0; c < 16; ++c) {
        #pragma unroll
        for (int r = 0; r < 4; ++r)
            xb[16 * w + 4 * qd + r][16 * c + l15] = f2bf(x1[c][r]);
    }
    __syncthreads();

    // ---- FFN-out + final residual + store ----
    #pragma unroll 1
    for (int half = 0; half < 2; ++half) {
        f32x4 f[8];
        #pragma unroll
        for (int c = 0; c < 8; ++c) f[c] = (f32x4){0.f,0.f,0.f,0.f};
        for (int kk = 0; kk < 8; ++kk) {
            const int k0 = 32 * kk;
            bf16x8 a = *(const bf16x8*)&xb[arow][k0 + 8 * qd];
            #pragma unroll
            for (int c = 0; c < 8; ++c) {
                const int n = 16 * (8 * half + c) + l15;
                bf16x8 bb = *(const bf16x8*)(Wo + n * DIM + k0 + 8 * qd);
                f[c] = __builtin_amdgcn_mfma_f32_16x16x32_bf16(a, bb, f[c], 0, 0, 0);
            }
        }
        #pragma unroll
        for (int c = 0; c < 8; ++c) {
            const int cg = 8 * half + c;
            const float bo = Bias[4 * DIM + 16 * cg + l15];
            #pragma unroll
            for (int r = 0; r < 4; ++r) {
                const int row = 16 * w + 4 * qd + r;
                if (row < NTOK) {
                    float o = 0.1f * (f[c][r] + bo) + 0.95f * x1[cg][r];
                    oblk[row * DIM + 16 * cg + l15] = o;
                }
            }
        }
    }
}

extern "C" void kernel_launch(void* const* d_in, const int* in_sizes, int n_in,
                              void* d_out, int out_size, void* d_ws, size_t ws_size,
                              hipStream_t stream) {
    const float* x = (const float*)d_in[0];
    short* Wt = (short*)d_ws;                                        // 5*256*256 bf16
    float* Bias = (float*)((char*)d_ws + (size_t)5 * DIM * DIM * 2); // 5*256 fp32
    static const int widx[5] = {1, 3, 5, 7, 9};
    for (int m = 0; m < 5; ++m) {
        prep_w<<<DIM, 64, 0, stream>>>((const float*)d_in[widx[m]], Wt + m * DIM * DIM);
        prep_b<<<NH, 64, 0, stream>>>((const float*)d_in[widx[m] + 1], Bias + m * DIM);
    }
    const int B = in_sizes[0] / (NTOK * DIM);
    irmb_main<<<B, 256, 0, stream>>>(x, Wt, Bias, (float*)d_out);
}

// Round 2
// 1259.663 us; speedup vs baseline: 1.5244x; 1.5244x over previous
//
#include <hip/hip_runtime.h>

#define DIM  256
#define NH   4
#define HC   64
#define NTOK 49

typedef short bf16x8 __attribute__((ext_vector_type(8)));
typedef short bf16x4 __attribute__((ext_vector_type(4)));
typedef float f32x4  __attribute__((ext_vector_type(4)));

#define MFMA(a, b, c) __builtin_amdgcn_mfma_f32_16x16x32_bf16((a), (b), (c), 0, 0, 0)
#define LGKM0() asm volatile("s_waitcnt lgkmcnt(0)" ::: "memory")

__device__ __forceinline__ short f2bf(float f) {
    union { float f; unsigned u; } v; v.f = f;
    unsigned r = v.u + 0x7fffu + ((v.u >> 16) & 1u);   // RNE
    return (short)(r >> 16);
}
__device__ __forceinline__ float bf2f(unsigned lo16) {
    union { unsigned u; float f; } v; v.u = lo16 << 16; return v.f;
}
__device__ __forceinline__ unsigned pack2(float a, float b) {
    return (unsigned)(unsigned short)f2bf(a) | ((unsigned)(unsigned short)f2bf(b) << 16);
}
__device__ __forceinline__ float wred_sum16(float v) {
    v += __shfl_xor(v, 1); v += __shfl_xor(v, 2);
    v += __shfl_xor(v, 4); v += __shfl_xor(v, 8);
    return v;
}
__device__ __forceinline__ float wred_max16(float v) {
    v = fmaxf(v, __shfl_xor(v, 1)); v = fmaxf(v, __shfl_xor(v, 2));
    v = fmaxf(v, __shfl_xor(v, 4)); v = fmaxf(v, __shfl_xor(v, 8));
    return v;
}

// Weight standardization + scatter into MFMA-fragment-major layout:
// for B-tile (nt, kk) of matrix `mat`, lane L's 16 B fragment lives at
// Wf[((mat*16+nt)*8+kk)*512 + L*8 .. +8], where lane L = (n&15) + 16*((k&31)>>3)
// holds B[n][k] = Wstd[k][n] for k in [32kk, 32kk+32), n in [16nt, 16nt+16).
__global__ void prep_w(const float* w0, const float* w1, const float* w2,
                       const float* w3, const float* w4, short* __restrict__ Wf) {
    const float* Ws[5] = {w0, w1, w2, w3, w4};
    const int mat  = blockIdx.y;
    const int k    = blockIdx.x;
    const int lane = threadIdx.x;      // 64 threads = one head-group
    const float* W = Ws[mat];
    #pragma unroll
    for (int h = 0; h < NH; ++h) {
        float w = W[k * DIM + h * HC + lane];
        float s1 = w, s2 = w * w;
        #pragma unroll
        for (int off = 1; off < 64; off <<= 1) {
            s1 += __shfl_xor(s1, off);
            s2 += __shfl_xor(s2, off);
        }
        float m   = s1 * 0.015625f;
        float var = s2 * 0.015625f - m * m;
        float inv = rsqrtf(fmaxf(var, 1e-30f)) * 0.0625f;   // 1/(popstd*sqrt(256))
        float val = (w - m) * inv;
        int n  = h * HC + lane;
        int nt = n >> 4, nl = n & 15;
        int kk = k >> 5, kl = k & 31;
        Wf[((mat * 16 + nt) * 8 + kk) * 512 + (nl + 16 * (kl >> 3)) * 8 + (kl & 7)] = f2bf(val);
    }
}

__global__ void prep_b(const float* b0, const float* b1, const float* b2,
                       const float* b3, const float* b4, float* __restrict__ Bias) {
    const float* Bs[5] = {b0, b1, b2, b3, b4};
    const int mat = blockIdx.y, h = blockIdx.x, lane = threadIdx.x;
    float w = Bs[mat][h * HC + lane];
    float s1 = w, s2 = w * w;
    #pragma unroll
    for (int off = 1; off < 64; off <<= 1) {
        s1 += __shfl_xor(s1, off);
        s2 += __shfl_xor(s2, off);
    }
    float m   = s1 * 0.015625f;
    float var = s2 * 0.015625f - m * m;
    float inv = rsqrtf(fmaxf(var, 1e-30f)) * 0.0625f;
    Bias[mat * DIM + h * HC + lane] = (w - m) * inv;
}

// One block = one batch item; 4 waves, wave w owns token rows [16w,16w+16).
// LDS phase-aliased: {qP,kb,vt} (attn) / xb (FFN transpose) / stg (store staging).
__global__ __launch_bounds__(256, 4) void irmb_main(
    const float* __restrict__ x, const short* __restrict__ Wf,
    const float* __restrict__ Bias, float* __restrict__ out)
{
    __shared__ __align__(16) char smem[33792];
    short (*qP)[72]  = (short (*)[72])smem;            //  9216 B, wave-row-private
    short (*kb)[72]  = (short (*)[72])(smem +  9216);  //  9216 B, shared
    short (*vt)[72]  = (short (*)[72])(smem + 18432);  //  9216 B, shared
    short (*xb)[264] = (short (*)[264])smem;           // 33792 B, wave-row-private
    float (*stg)[132] = (float (*)[132])smem;          // 33792 B, wave-row-private

    const int tid = threadIdx.x;
    const int w = tid >> 6, lane = tid & 63;
    const int l15 = lane & 15, qd = lane >> 4;
    const int arow = 16 * w + l15;

    const float* xblk = x + (size_t)blockIdx.x * (NTOK * DIM);
    float* oblk = out + (size_t)blockIdx.x * (NTOK * DIM);

    // ---- x A-fragments straight from global into registers ----
    bf16x8 ax[8];
    {
        const float* xr = xblk + arow * DIM;
        #pragma unroll
        for (int kk = 0; kk < 8; ++kk) {
            f32x4 u = {0.f,0.f,0.f,0.f}, v2 = {0.f,0.f,0.f,0.f};
            if (arow < NTOK) {
                u  = *(const f32x4*)(xr + 32 * kk + 8 * qd);
                v2 = *(const f32x4*)(xr + 32 * kk + 8 * qd + 4);
            }
            bf16x8 a;
            a[0]=f2bf(u[0]);  a[1]=f2bf(u[1]);  a[2]=f2bf(u[2]);  a[3]=f2bf(u[3]);
            a[4]=f2bf(v2[0]); a[5]=f2bf(v2[1]); a[6]=f2bf(v2[2]); a[7]=f2bf(v2[3]);
            ax[kk] = a;
        }
    }

    unsigned x1p[16][2];   // packed bf16 x1 (later x3), C-layout row pairs

    #pragma unroll
    for (int h = 0; h < NH; ++h) {
        float vf[4][4];
        unsigned kp[4][2];

        // ---- q/k/v GEMM for head h, two nt-halves (acc pressure 24 regs) ----
        #pragma unroll
        for (int H = 0; H < 2; ++H) {
            f32x4 qa[2], ka[2], va[2];
            #pragma unroll
            for (int t = 0; t < 2; ++t) {
                qa[t] = (f32x4){0.f,0.f,0.f,0.f};
                ka[t] = (f32x4){0.f,0.f,0.f,0.f};
                va[t] = (f32x4){0.f,0.f,0.f,0.f};
            }
            #pragma unroll
            for (int kk = 0; kk < 8; ++kk) {
                bf16x8 a = ax[kk];
                #pragma unroll
                for (int t = 0; t < 2; ++t) {
                    const int nt = 2 * H + t;
                    const short* bp = Wf + (size_t)((h * 4 + nt) * 8 + kk) * 512 + lane * 8;
                    bf16x8 bq = *(const bf16x8*)(bp);
                    bf16x8 bk = *(const bf16x8*)(bp + 65536);    // mat stride = 16*8*512
                    bf16x8 bv = *(const bf16x8*)(bp + 131072);
                    qa[t] = MFMA(a, bq, qa[t]);
                    ka[t] = MFMA(a, bk, ka[t]);
                    va[t] = MFMA(a, bv, va[t]);
                }
            }
            #pragma unroll
            for (int t = 0; t < 2; ++t) {
                const int nt = 2 * H + t;
                const int col = h * HC + 16 * nt + l15;
                const float bq = Bias[col], bk2 = Bias[DIM + col], bv = Bias[2 * DIM + col];
                #pragma unroll
                for (int r = 0; r < 4; ++r) {
                    const int row = 16 * w + 4 * qd + r;
                    qP[row][16 * nt + l15] = f2bf(qa[t][r] + bq);   // row-private, no barrier
                    float xh = (row < NTOK) ? xblk[row * DIM + col] : 0.f;
                    vf[nt][r] = 0.1f * (va[t][r] + bv) + 0.95f * xh;
                }
                kp[nt][0] = pack2(ka[t][0] + bk2, ka[t][1] + bk2);
                kp[nt][1] = pack2(ka[t][2] + bk2, ka[t][3] + bk2);
            }
        }

        if (h) __syncthreads();          // prior head's kb/vt reads complete
        #pragma unroll
        for (int nt = 0; nt < 4; ++nt) {
            #pragma unroll
            for (int rp = 0; rp < 2; ++rp) {
                kb[16 * w + 4 * qd + 2 * rp    ][16 * nt + l15] = (short)(kp[nt][rp] & 0xffff);
                kb[16 * w + 4 * qd + 2 * rp + 1][16 * nt + l15] = (short)(kp[nt][rp] >> 16);
            }
            bf16x4 vp;
            vp[0] = f2bf(vf[nt][0]); vp[1] = f2bf(vf[nt][1]);
            vp[2] = f2bf(vf[nt][2]); vp[3] = f2bf(vf[nt][3]);
            *(bf16x4*)&vt[16 * nt + l15][16 * w + 4 * qd] = vp;   // [channel][token]
        }
        __syncthreads();                 // kb/vt ready

        // ---- S = 0.125 * q @ k^T ----
        f32x4 sa[4];
        #pragma unroll
        for (int nt = 0; nt < 4; ++nt) sa[nt] = (f32x4){0.f,0.f,0.f,0.f};
        #pragma unroll
        for (int kk = 0; kk < 2; ++kk) {
            bf16x8 a = *(const bf16x8*)&qP[arow][32 * kk + 8 * qd];
            #pragma unroll
            for (int nt = 0; nt < 4; ++nt) {
                bf16x8 bb = *(const bf16x8*)&kb[16 * nt + l15][32 * kk + 8 * qd];
                sa[nt] = MFMA(a, bb, sa[nt]);
            }
        }

        // ---- softmax over keys (mask cols >= 49) ----
        float pmat[4][4];
        #pragma unroll
        for (int r = 0; r < 4; ++r) {
            float vals[4];
            #pragma unroll
            for (int nt = 0; nt < 4; ++nt) {
                const int ck = 16 * nt + l15;
                vals[nt] = (ck < NTOK) ? sa[nt][r] * 0.125f : -3.0e38f;
            }
            float mx = fmaxf(fmaxf(vals[0], vals[1]), fmaxf(vals[2], vals[3]));
            mx = wred_max16(mx);
            float sum = 0.f;
            #pragma unroll
            for (int nt = 0; nt < 4; ++nt) {
                const int ck = 16 * nt + l15;
                const float p = (ck < NTOK) ? __expf(vals[nt] - mx) : 0.f;
                pmat[nt][r] = p;
                sum += p;
            }
            sum = wred_sum16(sum);
            const float rs = 1.0f / sum;
            #pragma unroll
            for (int nt = 0; nt < 4; ++nt) pmat[nt][r] *= rs;
        }
        #pragma unroll
        for (int nt = 0; nt < 4; ++nt)
            #pragma unroll
            for (int r = 0; r < 4; ++r)
                qP[16 * w + 4 * qd + r][16 * nt + l15] = f2bf(pmat[nt][r]);
        LGKM0();   // same-wave cross-lane: P writes before A-frag reads

        // ---- x_spa = P @ v ; x1 = 0.1*x_spa + 0.95*v (packed bf16) ----
        f32x4 pa[4];
        #pragma unroll
        for (int nt = 0; nt < 4; ++nt) pa[nt] = (f32x4){0.f,0.f,0.f,0.f};
        #pragma unroll
        for (int kk = 0; kk < 2; ++kk) {
            bf16x8 a = *(const bf16x8*)&qP[arow][32 * kk + 8 * qd];
            #pragma unroll
            for (int nt = 0; nt < 4; ++nt) {
                bf16x8 bb = *(const bf16x8*)&vt[16 * nt + l15][32 * kk + 8 * qd];
                pa[nt] = MFMA(a, bb, pa[nt]);
            }
        }
        #pragma unroll
        for (int nt = 0; nt < 4; ++nt) {
            x1p[4 * h + nt][0] = pack2(0.1f * pa[nt][0] + 0.95f * vf[nt][0],
                                       0.1f * pa[nt][1] + 0.95f * vf[nt][1]);
            x1p[4 * h + nt][1] = pack2(0.1f * pa[nt][2] + 0.95f * vf[nt][2],
                                       0.1f * pa[nt][3] + 0.95f * vf[nt][3]);
        }
    }
    __syncthreads();   // attention fully done; xb may alias attn buffers now

    // ---- x1 -> xb (bf16, row-private), reload A-frags ----
    #pragma unroll
    for (int c = 0; c < 16; ++c)
        #pragma unroll
        for (int rp = 0; rp < 2; ++rp) {
            xb[16 * w + 4 * qd + 2 * rp    ][16 * c + l15] = (short)(x1p[c][rp] & 0xffff);
            xb[16 * w + 4 * qd + 2 * rp + 1][16 * c + l15] = (short)(x1p[c][rp] >> 16);
        }
    LGKM0();
    #pragma unroll
    for (int kk = 0; kk < 8; ++kk) ax[kk] = *(const bf16x8*)&xb[arow][32 * kk + 8 * qd];

    // ---- FFN-in + residual + sigmoid-residual ----
    #pragma unroll
    for (int half = 0; half < 2; ++half) {
        f32x4 f[8];
        #pragma unroll
        for (int c = 0; c < 8; ++c) f[c] = (f32x4){0.f,0.f,0.f,0.f};
        #pragma unroll
        for (int kk = 0; kk < 8; ++kk) {
            bf16x8 a = ax[kk];
            #pragma unroll
            for (int c = 0; c < 8; ++c) {
                const short* bp = Wf + (size_t)((48 + 8 * half + c) * 8 + kk) * 512 + lane * 8;
                f[c] = MFMA(a, *(const bf16x8*)bp, f[c]);
            }
        }
        #pragma unroll
        for (int c = 0; c < 8; ++c) {
            const int cg = 8 * half + c;
            const float bi = Bias[3 * DIM + 16 * cg + l15];
            #pragma unroll
            for (int rp = 0; rp < 2; ++rp) {
                float lo = bf2f(x1p[cg][rp] & 0xffff);
                float hi = bf2f(x1p[cg][rp] >> 16);
                float x2a = 0.1f * (f[c][2 * rp]     + bi) + 0.95f * lo;
                float x2b = 0.1f * (f[c][2 * rp + 1] + bi) + 0.95f * hi;
                float x3a = 0.95f * x2a + 0.1f * (1.0f / (1.0f + __expf(-x2a)) - 0.5f);
                float x3b = 0.95f * x2b + 0.1f * (1.0f / (1.0f + __expf(-x2b)) - 0.5f);
                x1p[cg][rp] = pack2(x3a, x3b);
            }
        }
    }

    // ---- x3 -> xb, reload A-frags ----
    #pragma unroll
    for (int c = 0; c < 16; ++c)
        #pragma unroll
        for (int rp = 0; rp < 2; ++rp) {
            xb[16 * w + 4 * qd + 2 * rp    ][16 * c + l15] = (short)(x1p[c][rp] & 0xffff);
            xb[16 * w + 4 * qd + 2 * rp + 1][16 * c + l15] = (short)(x1p[c][rp] >> 16);
        }
    LGKM0();
    #pragma unroll
    for (int kk = 0; kk < 8; ++kk) ax[kk] = *(const bf16x8*)&xb[arow][32 * kk + 8 * qd];
    __syncthreads();   // all waves hold x3 frags; stg may now clobber xb

    // ---- FFN-out + final residual, staged fp32 -> coalesced 512 B stores ----
    #pragma unroll
    for (int half = 0; half < 2; ++half) {
        f32x4 f[8];
        #pragma unroll
        for (int c = 0; c < 8; ++c) f[c] = (f32x4){0.f,0.f,0.f,0.f};
        #pragma unroll
        for (int kk = 0; kk < 8; ++kk) {
            bf16x8 a = ax[kk];
            #pragma unroll
            for (int c = 0; c < 8; ++c) {
                const short* bp = Wf + (size_t)((64 + 8 * half + c) * 8 + kk) * 512 + lane * 8;
                f[c] = MFMA(a, *(const bf16x8*)bp, f[c]);
            }
        }
        #pragma unroll
        for (int c = 0; c < 8; ++c) {
            const int cg = 8 * half + c;
            const float bo = Bias[4 * DIM + 16 * cg + l15];
            #pragma unroll
            for (int rp = 0; rp < 2; ++rp) {
                float lo = bf2f(x1p[cg][rp] & 0xffff);
                float hi = bf2f(x1p[cg][rp] >> 16);
                stg[16 * w + 4 * qd + 2 * rp    ][16 * c + l15] = 0.1f * (f[c][2 * rp]     + bo) + 0.95f * lo;
                stg[16 * w + 4 * qd + 2 * rp + 1][16 * c + l15] = 0.1f * (f[c][2 * rp + 1] + bo) + 0.95f * hi;
            }
        }
        LGKM0();   // stg writes complete (same-wave cross-lane)
        #pragma unroll
        for (int it = 0; it < 8; ++it) {
            const int row = 16 * w + 2 * it + (lane >> 5);
            if (row < NTOK) {
                f32x4 vv = *(const f32x4*)&stg[row][4 * (lane & 31)];
                *(f32x4*)(oblk + row * DIM + 128 * half + 4 * (lane & 31)) = vv;
            }
        }
        LGKM0();   // stg reads complete before next half overwrites
    }
}

extern "C" void kernel_launch(void* const* d_in, const int* in_sizes, int n_in,
                              void* d_out, int out_size, void* d_ws, size_t ws_size,
                              hipStream_t stream) {
    const float* x = (const float*)d_in[0];
    short* Wf  = (short*)d_ws;                                        // 5*128 tiles * 1 KB
    float* Bias = (float*)((char*)d_ws + (size_t)5 * DIM * DIM * 2);  // 5*256 fp32
    prep_w<<<dim3(DIM, 5), 64, 0, stream>>>(
        (const float*)d_in[1], (const float*)d_in[3], (const float*)d_in[5],
        (const float*)d_in[7], (const float*)d_in[9], Wf);
    prep_b<<<dim3(NH, 5), 64, 0, stream>>>(
        (const float*)d_in[2], (const float*)d_in[4], (const float*)d_in[6],
        (const float*)d_in[8], (const float*)d_in[10], Bias);
    const int B = in_sizes[0] / (NTOK * DIM);
    irmb_main<<<B, 256, 0, stream>>>(x, Wf, Bias, (float*)d_out);
}